// Round 6
// baseline (196.101 us; speedup 1.0000x reference)
//
#include <hip/hip_runtime.h>
#include <hip/hip_bf16.h>

#define B_    8
#define CIN   64
#define COUT  64
#define RN_   4
#define H_    128
#define W_    128
#define HW_   (H_ * W_)
#define BN_EPS 1e-5f

typedef short v8s __attribute__((ext_vector_type(8)));
typedef float v4f __attribute__((ext_vector_type(4)));

__device__ __forceinline__ unsigned short f2bf(float f) {
    unsigned int u = __float_as_uint(f);
    u += 0x7FFFu + ((u >> 16) & 1u);       // round-to-nearest-even
    return (unsigned short)(u >> 16);
}

// ---------------------------------------------------------------------------
// prep: merged transpose kernels (one launch)
//   blocks [0,1024):   x fp32 [b][c][h][w] -> xT bf16 [b][h][w][c]
//   blocks [1024,1152): kernel fp32 [b][r][o][c][t] -> kT bf16 [b][r][t][o][c]
// ---------------------------------------------------------------------------
__global__ __launch_bounds__(256) void prep(const float* __restrict__ x,
                                            const float* __restrict__ kr,
                                            unsigned short* __restrict__ xT,
                                            unsigned short* __restrict__ kT) {
    __shared__ float sl[16 * 64 * 9];                 // 36 KB (union of both uses)
    if (blockIdx.x < 1024) {
        const int b = blockIdx.x >> 7, h = blockIdx.x & 127;
        const float* xp = x + (size_t)b * CIN * HW_ + (size_t)h * W_;
        for (int idx = threadIdx.x; idx < CIN * W_; idx += 256) {
            const int c = idx >> 7, w = idx & 127;
            sl[c * 129 + w] = xp[(size_t)c * HW_ + w];
        }
        __syncthreads();
        unsigned short* op = xT + ((size_t)b * H_ + h) * (W_ * CIN);
        for (int idx = threadIdx.x; idx < (W_ * CIN) / 8; idx += 256) {
            const int w = idx >> 3, c0 = (idx & 7) << 3;
            int4 v;
            v.x = f2bf(sl[(c0 + 0) * 129 + w]) | ((unsigned)f2bf(sl[(c0 + 1) * 129 + w]) << 16);
            v.y = f2bf(sl[(c0 + 2) * 129 + w]) | ((unsigned)f2bf(sl[(c0 + 3) * 129 + w]) << 16);
            v.z = f2bf(sl[(c0 + 4) * 129 + w]) | ((unsigned)f2bf(sl[(c0 + 5) * 129 + w]) << 16);
            v.w = f2bf(sl[(c0 + 6) * 129 + w]) | ((unsigned)f2bf(sl[(c0 + 7) * 129 + w]) << 16);
            *(int4*)(op + (w << 6) + c0) = v;
        }
    } else {
        const int bid = blockIdx.x - 1024;
        const int br = bid >> 2, oq = bid & 3;
        const float* src = kr + ((size_t)br * 64 + oq * 16) * (64 * 9);
        for (int idx = threadIdx.x; idx < 2304; idx += 256)
            *(float4*)&sl[idx << 2] = *(const float4*)&src[idx << 2];
        __syncthreads();
        unsigned short* dst = kT + (size_t)br * (9 * 4096) + oq * (16 * 64);
        for (int idx = threadIdx.x; idx < 1152; idx += 256) {
            const int t = idx >> 7, rem = idx & 127, o16 = rem >> 3, c8 = (rem & 7) << 3;
            unsigned short s[8];
            #pragma unroll
            for (int j = 0; j < 8; j++)
                s[j] = f2bf(sl[(o16 * 64 + c8 + j) * 9 + t]);
            int4 v;
            v.x = s[0] | ((unsigned)s[1] << 16);
            v.y = s[2] | ((unsigned)s[3] << 16);
            v.z = s[4] | ((unsigned)s[5] << 16);
            v.w = s[6] | ((unsigned)s[7] << 16);
            *(int4*)(dst + t * 4096 + o16 * 64 + c8) = v;
        }
    }
}

// ---------------------------------------------------------------------------
// fused: dynamic grouped conv + mask conv/softmax (MFMA, fused) + region sum
// + BN + ReLU.  256 threads = 4 waves, 4 output rows/block.
// v4: A-fragments go global->VGPR double-buffered (kT is L2-resident; the
// a-frag address has no wave term, so LDS staging was 4x-redundant).
// K-loop is BARRIER-FREE (xs read-only after initial stage). All 36 K-steps
// emitted with literal RT via macro -> no dynamic register indexing (the
// round-3 spill cause). LDS 62 KB -> 2 blocks/CU.
// ---------------------------------------------------------------------------
#define WPAD     72                      // 36 dw; benign 2-way spread
#define XS_W     66                      // 64 + 2 halo columns
#define XS_ROWS  6                       // 4 output rows + 2 halo rows
#define XS_ELEMS (XS_ROWS * XS_W * WPAD) // 28512 shorts = 57 KB

__global__ __launch_bounds__(256, 2) void main_conv(
        const unsigned short* __restrict__ xT,
        const unsigned short* __restrict__ kT,
        const float* __restrict__ mw, const float* __restrict__ mb,
        const float* __restrict__ bn_gamma, const float* __restrict__ bn_beta,
        const float* __restrict__ bn_mean,  const float* __restrict__ bn_var,
        float* __restrict__ outp, float* __restrict__ masks_g) {
    __shared__ unsigned short xs[XS_ELEMS];
    __shared__ unsigned short mws[9 * 4 * 64];        // [tap][r][c] bf16, 4.5 KB
    __shared__ float scale_s[COUT];
    __shared__ float shift_s[COUT];

    const int tid = threadIdx.x;
    const int b  = blockIdx.z;
    const int w0 = blockIdx.y << 6;           // 0 or 64
    const int h0 = blockIdx.x << 2;           // 0..124
    const int lane = tid & 63, wv = tid >> 6; // wave wv owns output row h0+wv
    const int i = lane & 15, g = lane >> 4;
    const int h_out = h0 + wv;

    // lane base into kT: frag (rt,fm,ks) = ka + rt*4096 + fm*1024 + ks*32
    // (row = fm*16+i contributes i*64; col = ks*32+g*8 contributes g*8)
    const unsigned short* ka = kT + (size_t)b * (36 * 4096) + (i << 6) + (g << 3);

    v8s ab[2][8];                             // [parity][fm*2+ks]
    #pragma unroll
    for (int f = 0; f < 8; f++)               // prologue: rt=0
        ab[0][f] = *(const v8s*)(ka + ((f >> 1) << 10) + ((f & 1) << 5));

    // ---- stage x halo tile: rows h0-1..h0+4, cols w0-1..w0+64, 64 ch bf16 ----
    const unsigned short* xb = xT + (size_t)b * (HW_ * CIN);
    #pragma unroll
    for (int row = 0; row < XS_ROWS; row++) {
        const int h_in = h0 - 1 + row;
        const bool hok = (h_in >= 0) && (h_in < H_);
        for (int idx = tid; idx < XS_W * 8; idx += 256) {
            const int w = idx >> 3, c8 = (idx & 7) << 3;
            const int w_in = w0 - 1 + w;
            int4 v = make_int4(0, 0, 0, 0);
            if (hok && (w_in >= 0) && (w_in < W_))
                v = *(const int4*)(xb + ((h_in * W_ + w_in) << 6) + c8);
            *(int4*)(&xs[(row * XS_W + w) * WPAD + c8]) = v;
        }
    }
    // ---- stage mask weights: mws[tap][r][c] = bf16(mw[r][c][tap]) ----
    for (int idx = tid; idx < 9 * 4 * 64; idx += 256) {
        const int t = idx >> 8, rc = idx & 255, r = rc >> 6, c = rc & 63;
        mws[(t << 8) + (r << 6) + c] = f2bf(mw[((r << 6) + c) * 9 + t]);
    }
    if (tid < COUT) {
        const float sc = bn_gamma[tid] * rsqrtf(bn_var[tid] + BN_EPS);
        scale_s[tid] = sc;
        shift_s[tid] = bn_beta[tid] - bn_mean[tid] * sc;
    }
    const float mb0 = mb[0], mb1 = mb[1], mb2 = mb[2], mb3 = mb[3];

    // per-lane B-frag base (tap offset pre-biased so toff >= 0)
    int bbase[4];
    #pragma unroll
    for (int fn = 0; fn < 4; fn++)
        bbase[fn] = (wv * XS_W + fn * 16 + i) * WPAD + g * 8;

    v4f y_acc[4][4], o_acc[4][4], lg_acc[4];
    #pragma unroll
    for (int fm = 0; fm < 4; fm++)
        #pragma unroll
        for (int fn = 0; fn < 4; fn++) {
            y_acc[fm][fn] = (v4f){0.f, 0.f, 0.f, 0.f};
            o_acc[fm][fn] = (v4f){0.f, 0.f, 0.f, 0.f};
        }
    #pragma unroll
    for (int fn = 0; fn < 4; fn++) lg_acc[fn] = (v4f){0.f, 0.f, 0.f, 0.f};

    unsigned mk0[4], mk1[4];                  // bf16-packed masks [fn]: (r0|r1),(r2|r3)

    auto do_softmax = [&]() {
        #pragma unroll
        for (int fn = 0; fn < 4; fn++) {
            const float l0 = lg_acc[fn][0] + mb0, l1 = lg_acc[fn][1] + mb1;
            const float l2 = lg_acc[fn][2] + mb2, l3 = lg_acc[fn][3] + mb3;
            const float mx = fmaxf(fmaxf(l0, l1), fmaxf(l2, l3));
            const float e0 = __expf(l0 - mx), e1 = __expf(l1 - mx);
            const float e2 = __expf(l2 - mx), e3 = __expf(l3 - mx);
            const float inv = 1.f / (e0 + e1 + e2 + e3);
            const float m0 = e0 * inv, m1 = e1 * inv, m2 = e2 * inv, m3 = e3 * inv;
            if (g == 0) {                     // lanes 0..15 hold valid rows 0..3
                float* mp = masks_g + ((size_t)b * RN_ * H_ + h_out) * W_ + w0 + fn * 16 + i;
                mp[0] = m0; mp[HW_] = m1; mp[2 * HW_] = m2; mp[3 * HW_] = m3;
            }
            mk0[fn] = f2bf(m0) | ((unsigned)f2bf(m1) << 16);
            mk1[fn] = f2bf(m2) | ((unsigned)f2bf(m3) << 16);
        }
    };
    auto fold_region = [&](int r) {
        #pragma unroll
        for (int fn = 0; fn < 4; fn++) {
            unsigned pk = (r & 2) ? mk1[fn] : mk0[fn];
            pk = __shfl(pk, i);               // broadcast from g==0 lane of col i
            const float mv = (r & 1) ? __uint_as_float(pk & 0xffff0000u)
                                     : __uint_as_float(pk << 16);
            #pragma unroll
            for (int fm = 0; fm < 4; fm++) {
                o_acc[fm][fn] += mv * y_acc[fm][fn];
                y_acc[fm][fn] = (v4f){0.f, 0.f, 0.f, 0.f};
            }
        }
    };

    __syncthreads();                          // the ONLY barrier

#define RT_STEP(RT)                                                              \
    {                                                                            \
        constexpr int cur = (RT) & 1, nxt = cur ^ 1;                             \
        if ((RT) < 35) {                                                         \
            const unsigned short* kn = ka + (((RT) + 1) << 12);                  \
            _Pragma("unroll")                                                    \
            for (int f = 0; f < 8; f++)                                          \
                ab[nxt][f] = *(const v8s*)(kn + ((f >> 1) << 10) + ((f & 1) << 5)); \
        }                                                                        \
        constexpr int tap = (RT) % 9;                                            \
        constexpr int toff = ((tap / 3) * XS_W + (tap % 3)) * WPAD;              \
        _Pragma("unroll")                                                        \
        for (int ks = 0; ks < 2; ks++) {                                         \
            v8s bfr[4];                                                          \
            _Pragma("unroll")                                                    \
            for (int fn = 0; fn < 4; fn++)                                       \
                bfr[fn] = *(const v8s*)(&xs[bbase[fn] + toff + ks * 32]);        \
            if ((RT) < 9) {                                                      \
                const v8s am = *(const v8s*)(&mws[(tap << 8) + ((i & 3) << 6) + ks * 32 + g * 8]); \
                _Pragma("unroll")                                                \
                for (int fn = 0; fn < 4; fn++)                                   \
                    lg_acc[fn] = __builtin_amdgcn_mfma_f32_16x16x32_bf16(        \
                        am, bfr[fn], lg_acc[fn], 0, 0, 0);                       \
            }                                                                    \
            _Pragma("unroll")                                                    \
            for (int fm = 0; fm < 4; fm++)                                       \
                _Pragma("unroll")                                                \
                for (int fn = 0; fn < 4; fn++)                                   \
                    y_acc[fm][fn] = __builtin_amdgcn_mfma_f32_16x16x32_bf16(     \
                        ab[cur][fm * 2 + ks], bfr[fn], y_acc[fm][fn], 0, 0, 0);  \
        }                                                                        \
        if ((RT) == 8) do_softmax();                                             \
        if (tap == 8) fold_region((RT) / 9);                                     \
    }

    RT_STEP(0)  RT_STEP(1)  RT_STEP(2)  RT_STEP(3)  RT_STEP(4)  RT_STEP(5)
    RT_STEP(6)  RT_STEP(7)  RT_STEP(8)  RT_STEP(9)  RT_STEP(10) RT_STEP(11)
    RT_STEP(12) RT_STEP(13) RT_STEP(14) RT_STEP(15) RT_STEP(16) RT_STEP(17)
    RT_STEP(18) RT_STEP(19) RT_STEP(20) RT_STEP(21) RT_STEP(22) RT_STEP(23)
    RT_STEP(24) RT_STEP(25) RT_STEP(26) RT_STEP(27) RT_STEP(28) RT_STEP(29)
    RT_STEP(30) RT_STEP(31) RT_STEP(32) RT_STEP(33) RT_STEP(34) RT_STEP(35)
#undef RT_STEP

    // ---- epilogue: BN + ReLU + store (C/D: n = i, m = g*4+reg within fm*16) ----
    #pragma unroll
    for (int fm = 0; fm < 4; fm++) {
        #pragma unroll
        for (int reg = 0; reg < 4; reg++) {
            const int o = fm * 16 + g * 4 + reg;
            const float sc = scale_s[o], sh = shift_s[o];
            float* rowp = outp + (((size_t)b * COUT + o) * H_ + h_out) * W_ + w0 + i;
            #pragma unroll
            for (int fn = 0; fn < 4; fn++) {
                const float v = o_acc[fm][fn][reg] * sc + sh;
                rowp[fn * 16] = fmaxf(v, 0.f);
            }
        }
    }
}

// ---------------------------------------------------------------------------
extern "C" void kernel_launch(void* const* d_in, const int* in_sizes, int n_in,
                              void* d_out, int out_size, void* d_ws, size_t ws_size,
                              hipStream_t stream) {
    const float* x     = (const float*)d_in[0];
    const float* kr    = (const float*)d_in[1];
    const float* mw    = (const float*)d_in[2];
    const float* mb    = (const float*)d_in[3];
    const float* gamma = (const float*)d_in[4];
    const float* beta  = (const float*)d_in[5];
    const float* mean  = (const float*)d_in[6];
    const float* var   = (const float*)d_in[7];

    float* outp  = (float*)d_out;
    float* masks = outp + (size_t)B_ * COUT * HW_;          // output #2 region

    unsigned short* xT = (unsigned short*)d_ws;             // 16 MB
    unsigned short* kT = xT + (size_t)B_ * HW_ * CIN;       // +2.25 MB

    hipLaunchKernelGGL(prep, dim3(1152), dim3(256), 0, stream, x, kr, xT, kT);
    hipLaunchKernelGGL(main_conv, dim3(H_ / 4, 2, B_), dim3(256), 0, stream,
                       xT, kT, mw, mb, gamma, beta, mean, var, outp, masks);
}